// Round 1
// baseline (638.515 us; speedup 1.0000x reference)
//
#include <hip/hip_runtime.h>

// Problem constants
#define S_TOK 4096
#define D_DIM 4096
#define O_DIM 4096
#define R_DIM 256
#define E_EXP 8
#define NTOK  8192   // B*S
#define MAXTILES 96  // worst case 71

typedef __bf16 bf16x8 __attribute__((ext_vector_type(8)));
typedef float  f32x4  __attribute__((ext_vector_type(4)));

__device__ __forceinline__ unsigned short f2bf(float f) {
  unsigned int u = __float_as_uint(f);
  u += 0x7FFFu + ((u >> 16) & 1u);   // RNE (no NaN in data)
  return (unsigned short)(u >> 16);
}

__device__ __forceinline__ void gload_lds16(const unsigned short* g, unsigned short* l) {
  __builtin_amdgcn_global_load_lds((const __attribute__((address_space(1))) void*)g,
                                   (__attribute__((address_space(3))) void*)l, 16, 0, 0);
}

// ---------------- cast f32 -> bf16, 8 elems/thread ----------------
__global__ void cast8(const float* __restrict__ in, unsigned short* __restrict__ out) {
  size_t g = (size_t)blockIdx.x * 256 + threadIdx.x;
  const float4* i4 = (const float4*)in;
  float4 a = i4[g * 2], b = i4[g * 2 + 1];
  union { unsigned short h[8]; int4 v; } u;
  u.h[0] = f2bf(a.x); u.h[1] = f2bf(a.y); u.h[2] = f2bf(a.z); u.h[3] = f2bf(a.w);
  u.h[4] = f2bf(b.x); u.h[5] = f2bf(b.y); u.h[6] = f2bf(b.z); u.h[7] = f2bf(b.w);
  ((int4*)out)[g] = u.v;
}

// ------------- transpose+cast: in[e][P][Q] f32 -> out[e][Q][P] bf16 -------------
__global__ void transpose_cast(const float* __restrict__ in, unsigned short* __restrict__ out,
                               int P, int Q) {
  __shared__ unsigned short tile[32][33];
  int e = blockIdx.z;
  int pt = blockIdx.x * 32, qt = blockIdx.y * 32;
  const float* ie = in + (size_t)e * P * Q;
  unsigned short* oe = out + (size_t)e * P * Q;
  int tx = threadIdx.x & 31, ty = threadIdx.x >> 5;
  #pragma unroll
  for (int i = 0; i < 32; i += 8) {
    int p = pt + ty + i, q = qt + tx;
    tile[ty + i][tx] = f2bf(ie[(size_t)p * Q + q]);
  }
  __syncthreads();
  #pragma unroll
  for (int i = 0; i < 32; i += 8) {
    int q = qt + ty + i, p = pt + tx;
    oe[(size_t)q * P + p] = tile[tx][ty + i];
  }
}

// ------------- deterministic stable counting sort of tokens by expert -------------
__global__ void sort_tokens(const int* __restrict__ tt, int* __restrict__ token_perm,
                            int* __restrict__ tile_e, int* __restrict__ tile_j0,
                            int* __restrict__ tile_jend, int* __restrict__ ntiles_out) {
  __shared__ int ltt[S_TOK];
  __shared__ int lc[256 * 8];
  __shared__ int basee[8], cnte[8];
  __shared__ int ssl[S_TOK];
  int t = threadIdx.x;
  for (int s = t; s < S_TOK; s += 256) ltt[s] = tt[s];
  __syncthreads();
  int c[8] = {0,0,0,0,0,0,0,0};
  #pragma unroll
  for (int i = 0; i < 16; i++) { int e = ltt[t * 16 + i]; c[e]++; }
  #pragma unroll
  for (int e = 0; e < 8; e++) lc[t * 8 + e] = c[e];
  __syncthreads();
  if (t < 8) {
    int run = 0;
    for (int q = 0; q < 256; q++) { int tmp = lc[q * 8 + t]; lc[q * 8 + t] = run; run += tmp; }
    cnte[t] = run;
  }
  __syncthreads();
  if (t == 0) { int tot = 0; for (int e = 0; e < 8; e++) { basee[e] = tot; tot += cnte[e]; } }
  __syncthreads();
  int off[8];
  #pragma unroll
  for (int e = 0; e < 8; e++) off[e] = basee[e] + lc[t * 8 + e];
  #pragma unroll
  for (int i = 0; i < 16; i++) { int s = t * 16 + i; int e = ltt[s]; ssl[off[e]++] = s; }
  __syncthreads();
  for (int j = t; j < NTOK; j += 256) token_perm[j] = ((j & 1) << 12) + ssl[j >> 1];
  if (t == 0) {
    int nt = 0;
    for (int e = 0; e < 8; e++) {
      int js = 2 * basee[e], je = js + 2 * cnte[e];
      for (int j0 = js; j0 < je; j0 += 128) {
        tile_e[nt] = e; tile_j0[nt] = j0;
        tile_jend[nt] = (je < j0 + 128) ? je : (j0 + 128);
        nt++;
      }
    }
    *ntiles_out = nt;
  }
}

// ------------- NT GEMM skeleton: 128x128 tile, BK=32, 4 waves, mfma 16x16x32 bf16 -------------
// MODE 0: out_f32[row][col] = X @ W^T             (rows direct, dense)
// MODE 1: H16s[j][r]       = X[perm[j]] @ A16t[e]^T  (gathered rows, bf16 out, predicated)
// MODE 2: out_f32[perm[j]] += 2 * H16s @ B16t[e]^T   (scatter-RMW, predicated)
template<int MODE>
__global__ __launch_bounds__(256, 2) void gemm_nt(
    const unsigned short* __restrict__ Aop, const unsigned short* __restrict__ Bop,
    float* __restrict__ outF, unsigned short* __restrict__ outH,
    const int* __restrict__ perm, const int* __restrict__ tile_e,
    const int* __restrict__ tile_j0, const int* __restrict__ tile_jend,
    const int* __restrict__ ntiles, int K) {
  int bm = blockIdx.x, bn = blockIdx.y;
  int e = 0, j0 = 0, jend = 0, row0 = 0;
  if (MODE == 0) {
    row0 = bm * 128;
  } else {
    if (bm >= *ntiles) return;
    e = tile_e[bm]; j0 = tile_j0[bm]; jend = tile_jend[bm];
  }
  const int t = threadIdx.x;
  const int l = t & 63, w = t >> 6;
  __shared__ __align__(16) unsigned short lA[128 * 32];
  __shared__ __align__(16) unsigned short lB[128 * 32];

  const unsigned short* srcA[2];
  const unsigned short* srcB[2];
  #pragma unroll
  for (int ck = 0; ck < 2; ck++) {
    int idx = t + ck * 256;
    int lrow = idx >> 2, lk = (idx & 3) * 8;
    const unsigned short* ap;
    if (MODE == 0) {
      ap = Aop + (size_t)(row0 + lrow) * K;
    } else {
      int j = j0 + lrow; if (j > jend - 1) j = jend - 1;
      int grow = (MODE == 1) ? perm[j] : j;
      ap = Aop + (size_t)grow * K;
    }
    srcA[ck] = ap + lk;
    int bcol = bn * 128 + lrow;
    const unsigned short* bp = Bop;
    if (MODE == 1) bp += (size_t)e * R_DIM * D_DIM;
    if (MODE == 2) bp += (size_t)e * O_DIM * R_DIM;
    srcB[ck] = bp + (size_t)bcol * K + lk;
  }

  f32x4 acc[4][4];
  #pragma unroll
  for (int m = 0; m < 4; m++)
    #pragma unroll
    for (int n = 0; n < 4; n++) acc[m][n] = (f32x4){0.f, 0.f, 0.f, 0.f};

  const int wr = w >> 1, wc = w & 1;
  const int ra = wr * 64 + (l & 15);
  const int rb = wc * 64 + (l & 15);
  const int ko = (l >> 4) * 8;

  const int nk = K / 32;
  for (int kt = 0; kt < nk; kt++) {
    __syncthreads();
    #pragma unroll
    for (int ck = 0; ck < 2; ck++) {
      gload_lds16(srcA[ck] + kt * 32, &lA[(w * 64 + ck * 256) * 8]);
      gload_lds16(srcB[ck] + kt * 32, &lB[(w * 64 + ck * 256) * 8]);
    }
    __syncthreads();
    bf16x8 af[4], bfr[4];
    #pragma unroll
    for (int m = 0; m < 4; m++) af[m] = *(const bf16x8*)&lA[(ra + m * 16) * 32 + ko];
    #pragma unroll
    for (int n = 0; n < 4; n++) bfr[n] = *(const bf16x8*)&lB[(rb + n * 16) * 32 + ko];
    #pragma unroll
    for (int m = 0; m < 4; m++)
      #pragma unroll
      for (int n = 0; n < 4; n++)
        acc[m][n] = __builtin_amdgcn_mfma_f32_16x16x32_bf16(af[m], bfr[n], acc[m][n], 0, 0, 0);
  }

  int rowbase = ((MODE == 0) ? row0 : j0) + wr * 64;
  int colbase = bn * 128 + wc * 64;
  #pragma unroll
  for (int m = 0; m < 4; m++) {
    #pragma unroll
    for (int n = 0; n < 4; n++) {
      #pragma unroll
      for (int v = 0; v < 4; v++) {
        int r = rowbase + m * 16 + (l >> 4) * 4 + v;
        int cc = colbase + n * 16 + (l & 15);
        if (MODE == 0) {
          outF[(size_t)r * O_DIM + cc] = acc[m][n][v];
        } else if (MODE == 1) {
          if (r < jend) outH[(size_t)r * R_DIM + cc] = f2bf(acc[m][n][v]);
        } else {
          if (r < jend) {
            size_t o = (size_t)perm[r] * O_DIM + cc;
            outF[o] += 2.0f * acc[m][n][v];
          }
        }
      }
    }
  }
}

// ---------------- workspace layout (bytes) ----------------
#define X16_OFF   ((size_t)0)             // 8192*4096*2   = 67108864
#define W16_OFF   ((size_t)67108864)      // 4096*4096*2   = 33554432
#define A16T_OFF  ((size_t)100663296)     // 8*256*4096*2  = 16777216  [E][R][D]
#define B16T_OFF  ((size_t)117440512)     // 8*4096*256*2  = 16777216  [E][O][R]
#define H16S_OFF  ((size_t)134217728)     // 8192*256*2    = 4194304
#define PERM_OFF  ((size_t)138412032)     // 8192*4
#define TILEE_OFF ((size_t)138444800)     // 96*4
#define TILEJ0_OFF ((size_t)138445184)
#define TILEJE_OFF ((size_t)138445568)
#define NT_OFF    ((size_t)138445952)

extern "C" void kernel_launch(void* const* d_in, const int* in_sizes, int n_in,
                              void* d_out, int out_size, void* d_ws, size_t ws_size,
                              hipStream_t stream) {
  const float* x  = (const float*)d_in[0];   // [2,4096,4096]
  const float* wb = (const float*)d_in[1];   // [4096,4096]
  const float* la = (const float*)d_in[2];   // [8,4096,256]
  const float* lb = (const float*)d_in[3];   // [8,256,4096]
  const int* tok  = (const int*)d_in[4];     // [4096]
  float* out = (float*)d_out;                // [2,4096,4096]

  char* ws = (char*)d_ws;
  unsigned short* X16  = (unsigned short*)(ws + X16_OFF);
  unsigned short* W16  = (unsigned short*)(ws + W16_OFF);
  unsigned short* A16t = (unsigned short*)(ws + A16T_OFF);
  unsigned short* B16t = (unsigned short*)(ws + B16T_OFF);
  unsigned short* H16s = (unsigned short*)(ws + H16S_OFF);
  int* perm  = (int*)(ws + PERM_OFF);
  int* tl_e  = (int*)(ws + TILEE_OFF);
  int* tl_j0 = (int*)(ws + TILEJ0_OFF);
  int* tl_je = (int*)(ws + TILEJE_OFF);
  int* nt    = (int*)(ws + NT_OFF);

  // casts
  cast8<<<16384, 256, 0, stream>>>(x, X16);            // 33554432 elems
  cast8<<<8192, 256, 0, stream>>>(wb, W16);            // 16777216 elems
  transpose_cast<<<dim3(128, 8, 8), 256, 0, stream>>>(la, A16t, D_DIM, R_DIM);
  transpose_cast<<<dim3(8, 128, 8), 256, 0, stream>>>(lb, B16t, R_DIM, O_DIM);
  // sort tokens by expert (deterministic)
  sort_tokens<<<1, 256, 0, stream>>>(tok, perm, tl_e, tl_j0, tl_je, nt);
  // base GEMM: out = X @ W^T
  gemm_nt<0><<<dim3(64, 32), 256, 0, stream>>>(X16, W16, out, nullptr,
                                               perm, tl_e, tl_j0, tl_je, nt, D_DIM);
  // LoRA stage 1: H_sorted = X[perm] @ A_e^T
  gemm_nt<1><<<dim3(71, 2), 256, 0, stream>>>(X16, A16t, nullptr, H16s,
                                              perm, tl_e, tl_j0, tl_je, nt, D_DIM);
  // LoRA stage 2: out[perm] += 2 * H_sorted @ B_e^T
  gemm_nt<2><<<dim3(71, 32), 256, 0, stream>>>(H16s, B16t, out, nullptr,
                                               perm, tl_e, tl_j0, tl_je, nt, R_DIM);
}

// Round 4
// 628.026 us; speedup vs baseline: 1.0167x; 1.0167x over previous
//
#include <hip/hip_runtime.h>

// Problem constants
#define S_TOK 4096
#define D_DIM 4096
#define O_DIM 4096
#define R_DIM 256
#define E_EXP 8
#define NTOK  8192   // B*S
#define KSPLIT 4

typedef __bf16 bf16x8 __attribute__((ext_vector_type(8)));
typedef float  f32x4  __attribute__((ext_vector_type(4)));

__device__ __forceinline__ unsigned short f2bf(float f) {
  unsigned int u = __float_as_uint(f);
  u += 0x7FFFu + ((u >> 16) & 1u);   // RNE (no NaN in data)
  return (unsigned short)(u >> 16);
}

__device__ __forceinline__ void gload_lds16(const unsigned short* g, unsigned short* l) {
  __builtin_amdgcn_global_load_lds((const __attribute__((address_space(1))) void*)g,
                                   (__attribute__((address_space(3))) void*)l, 16, 0, 0);
}

// Fused counted-wait + barrier as ONE volatile asm with memory clobber.
#define PIPE_FENCE(N)                                                        \
  do {                                                                       \
    asm volatile("s_waitcnt vmcnt(" #N ")\n\ts_barrier" ::: "memory");       \
    __builtin_amdgcn_sched_barrier(0);                                       \
  } while (0)

// ---------------- cast f32 -> bf16, 8 elems/thread ----------------
__global__ void cast8(const float* __restrict__ in, unsigned short* __restrict__ out) {
  size_t g = (size_t)blockIdx.x * 256 + threadIdx.x;
  const float4* i4 = (const float4*)in;
  float4 a = i4[g * 2], b = i4[g * 2 + 1];
  union { unsigned short h[8]; int4 v; } u;
  u.h[0] = f2bf(a.x); u.h[1] = f2bf(a.y); u.h[2] = f2bf(a.z); u.h[3] = f2bf(a.w);
  u.h[4] = f2bf(b.x); u.h[5] = f2bf(b.y); u.h[6] = f2bf(b.z); u.h[7] = f2bf(b.w);
  ((int4*)out)[g] = u.v;
}

// ------------- transpose+cast: in[e][P][Q] f32 -> out[e][Q][P] bf16 -------------
__global__ void transpose_cast(const float* __restrict__ in, unsigned short* __restrict__ out,
                               int P, int Q) {
  __shared__ unsigned short tile[32][33];
  int e = blockIdx.z;
  int pt = blockIdx.x * 32, qt = blockIdx.y * 32;
  const float* ie = in + (size_t)e * P * Q;
  unsigned short* oe = out + (size_t)e * P * Q;
  int tx = threadIdx.x & 31, ty = threadIdx.x >> 5;
  #pragma unroll
  for (int i = 0; i < 32; i += 8) {
    int p = pt + ty + i, q = qt + tx;
    tile[ty + i][tx] = f2bf(ie[(size_t)p * Q + q]);
  }
  __syncthreads();
  #pragma unroll
  for (int i = 0; i < 32; i += 8) {
    int q = qt + ty + i, p = pt + tx;
    oe[(size_t)q * P + p] = tile[tx][ty + i];
  }
}

// ------------- deterministic stable counting sort of tokens by expert -------------
__global__ void sort_tokens(const int* __restrict__ tt, int* __restrict__ token_perm,
                            int* __restrict__ tile_e, int* __restrict__ tile_j0,
                            int* __restrict__ tile_jend, int* __restrict__ ntiles_out) {
  __shared__ int ltt[S_TOK];
  __shared__ int lc[256 * 8];
  __shared__ int basee[8], cnte[8];
  __shared__ int ssl[S_TOK];
  int t = threadIdx.x;
  for (int s = t; s < S_TOK; s += 256) ltt[s] = tt[s];
  __syncthreads();
  int c[8] = {0,0,0,0,0,0,0,0};
  #pragma unroll
  for (int i = 0; i < 16; i++) { int e = ltt[t * 16 + i]; c[e]++; }
  #pragma unroll
  for (int e = 0; e < 8; e++) lc[t * 8 + e] = c[e];
  __syncthreads();
  if (t < 8) {
    int run = 0;
    for (int q = 0; q < 256; q++) { int tmp = lc[q * 8 + t]; lc[q * 8 + t] = run; run += tmp; }
    cnte[t] = run;
  }
  __syncthreads();
  if (t == 0) { int tot = 0; for (int e = 0; e < 8; e++) { basee[e] = tot; tot += cnte[e]; } }
  __syncthreads();
  int off[8];
  #pragma unroll
  for (int e = 0; e < 8; e++) off[e] = basee[e] + lc[t * 8 + e];
  #pragma unroll
  for (int i = 0; i < 16; i++) { int s = t * 16 + i; int e = ltt[s]; ssl[off[e]++] = s; }
  __syncthreads();
  for (int j = t; j < NTOK; j += 256) token_perm[j] = ((j & 1) << 12) + ssl[j >> 1];
  if (t == 0) {
    int nt = 0;
    for (int e = 0; e < 8; e++) {
      int js = 2 * basee[e], je = js + 2 * cnte[e];
      for (int j0 = js; j0 < je; j0 += 128) {
        tile_e[nt] = e; tile_j0[nt] = j0;
        tile_jend[nt] = (je < j0 + 128) ? je : (j0 + 128);
        nt++;
      }
    }
    *ntiles_out = nt;
  }
}

// ===================== 256x256 deep-pipelined dense GEMM =====================
// C[8192][4096] = A[8192][4096] @ B[4096][4096]^T, bf16 in, f32 out.
// 8 waves (2Mx4N), BK=32, 4 LDS buffers (128 KiB), counted vmcnt, T2 swizzle.
// vmcnt ledger: stage() = 4 loads/wave. Main loop (kt stages tile kt+3):
//   fence vmcnt(8) => tiles kt+2,kt+3 in flight, tile kt+1 LANDED.
// Tail (no more staging): descending drain 8 -> 4 -> 0 so tiles NKT-2, NKT-1
// are guaranteed landed before their reads (Round 2/3 race was here).
__global__ __launch_bounds__(512, 2) void gemm256_dense(
    const unsigned short* __restrict__ A, const unsigned short* __restrict__ B,
    float* __restrict__ C) {
  constexpr int K = 4096, NKT = 128;
  __shared__ __align__(16) unsigned short lds[4][2][256 * 32];
  int wg = blockIdx.x;
  wg = (wg & 7) * 64 + (wg >> 3);          // XCD swizzle (512 % 8 == 0, bijective)
  const int bm = wg & 31, bn = wg >> 5;    // 32 x 16 tiles
  const int t = threadIdx.x, l = t & 63, w = t >> 6;
  const int wm = w >> 2, wn = w & 3;

  // staging source pointers (inverse-swizzled global source, linear LDS dest)
  const unsigned short* pA[2];
  const unsigned short* pB[2];
  #pragma unroll
  for (int ck = 0; ck < 2; ck++) {
    int idx = ck * 512 + t;
    int row = idx >> 2;
    int k16 = (idx & 3) * 16;                                // byte col in 64B row
    int srck = (k16 ^ (((row >> 1) & 3) << 4)) >> 1;         // element offset [0,32)
    pA[ck] = A + (size_t)(bm * 256 + row) * K + srck;
    pB[ck] = B + (size_t)(bn * 256 + row) * K + srck;
  }

  // swizzled LDS read byte-offsets (within one buffer; operand B at +16384B)
  const int lane15 = l & 15, kb = (l >> 4) * 16;
  int offA[8], offB[4];
  #pragma unroll
  for (int m = 0; m < 8; m++) {
    int row = wm * 128 + m * 16 + lane15;
    offA[m] = row * 64 + (kb ^ (((row >> 1) & 3) << 4));
  }
  #pragma unroll
  for (int n = 0; n < 4; n++) {
    int row = wn * 64 + n * 16 + lane15;
    offB[n] = 16384 + row * 64 + (kb ^ (((row >> 1) & 3) << 4));
  }

  f32x4 acc[8][4];
  #pragma unroll
  for (int m = 0; m < 8; m++)
    #pragma unroll
    for (int n = 0; n < 4; n++) acc[m][n] = (f32x4){0.f, 0.f, 0.f, 0.f};

  auto stage = [&](int bi) {
    unsigned short* la = &lds[bi][0][0];
    unsigned short* lb = &lds[bi][1][0];
    #pragma unroll
    for (int ck = 0; ck < 2; ck++) {
      gload_lds16(pA[ck], la + (ck * 512 + w * 64) * 8);
      gload_lds16(pB[ck], lb + (ck * 512 + w * 64) * 8);
      pA[ck] += 32; pB[ck] += 32;
    }
  };

  auto compute = [&](int bi) {
    const char* base = (const char*)&lds[bi][0][0];
    bf16x8 a[8], b[4];
    #pragma unroll
    for (int m = 0; m < 8; m++) a[m] = *(const bf16x8*)(base + offA[m]);
    #pragma unroll
    for (int n = 0; n < 4; n++) b[n] = *(const bf16x8*)(base + offB[n]);
    __builtin_amdgcn_s_setprio(1);
    #pragma unroll
    for (int m = 0; m < 8; m++)
      #pragma unroll
      for (int n = 0; n < 4; n++)
        acc[m][n] = __builtin_amdgcn_mfma_f32_16x16x32_bf16(a[m], b[n], acc[m][n], 0, 0, 0);
    __builtin_amdgcn_s_setprio(0);
  };

  // prologue: 3 tiles in flight (12 loads), wait => tile 0 landed
  stage(0); stage(1); stage(2);
  PIPE_FENCE(8);

  // main loop: compute tiles 0 .. NKT-4, staging unconditional
  #pragma unroll 4
  for (int kt = 0; kt < NKT - 3; ++kt) {
    stage((kt + 3) & 3);     // overwrites buffer of tile kt-1 (read finished)
    compute(kt & 3);
    PIPE_FENCE(8);           // tile kt+1 landed; kt+2, kt+3 in flight
  }
  // tail: tiles NKT-3, NKT-2, NKT-1 with descending drain
  compute((NKT - 3) & 3);
  PIPE_FENCE(4);             // tile NKT-2 landed
  compute((NKT - 2) & 3);
  PIPE_FENCE(0);             // tile NKT-1 landed
  compute((NKT - 1) & 3);

  const int rowbase = bm * 256 + wm * 128;
  const int colbase = bn * 256 + wn * 64;
  #pragma unroll
  for (int m = 0; m < 8; m++)
    #pragma unroll
    for (int n = 0; n < 4; n++)
      #pragma unroll
      for (int v = 0; v < 4; v++) {
        int r = rowbase + m * 16 + (l >> 4) * 4 + v;
        int cc = colbase + n * 16 + lane15;
        C[(size_t)r * O_DIM + cc] = acc[m][n][v];
      }
}

// ------------- 128x128 skeleton for the LoRA GEMMs -------------
// MODE 1: Hp[kc][j][r] = partial( X[perm[j]] @ A16t[e]^T ) over K-chunk kc (f32 out)
// MODE 2: out_f32[perm[j]] += 2 * H16s @ B16t[e]^T   (scatter-RMW, predicated)
template<int MODE>
__global__ __launch_bounds__(256, 2) void gemm_nt(
    const unsigned short* __restrict__ Aop, const unsigned short* __restrict__ Bop,
    float* __restrict__ outF,
    const int* __restrict__ perm, const int* __restrict__ tile_e,
    const int* __restrict__ tile_j0, const int* __restrict__ tile_jend,
    const int* __restrict__ ntiles, int K) {
  int bm = blockIdx.x, bn = blockIdx.y;
  if (bm >= *ntiles) return;
  int e = tile_e[bm], j0 = tile_j0[bm], jend = tile_jend[bm];
  const int kc = (MODE == 1) ? blockIdx.z : 0;
  const int t = threadIdx.x;
  const int l = t & 63, w = t >> 6;
  __shared__ __align__(16) unsigned short lA[128 * 32];
  __shared__ __align__(16) unsigned short lB[128 * 32];

  const unsigned short* srcA[2];
  const unsigned short* srcB[2];
  #pragma unroll
  for (int ck = 0; ck < 2; ck++) {
    int idx = t + ck * 256;
    int lrow = idx >> 2, lk = (idx & 3) * 8;
    int j = j0 + lrow; if (j > jend - 1) j = jend - 1;
    int grow = (MODE == 1) ? perm[j] : j;
    srcA[ck] = Aop + (size_t)grow * K + lk + kc * 1024;
    int bcol = bn * 128 + lrow;
    const unsigned short* bp = Bop;
    if (MODE == 1) bp += (size_t)e * R_DIM * D_DIM;
    if (MODE == 2) bp += (size_t)e * O_DIM * R_DIM;
    srcB[ck] = bp + (size_t)bcol * K + lk + kc * 1024;
  }

  f32x4 acc[4][4];
  #pragma unroll
  for (int m = 0; m < 4; m++)
    #pragma unroll
    for (int n = 0; n < 4; n++) acc[m][n] = (f32x4){0.f, 0.f, 0.f, 0.f};

  const int wr = w >> 1, wc = w & 1;
  const int ra = wr * 64 + (l & 15);
  const int rb = wc * 64 + (l & 15);
  const int ko = (l >> 4) * 8;

  const int nk = (MODE == 1) ? (1024 / 32) : (K / 32);
  for (int kt = 0; kt < nk; kt++) {
    __syncthreads();
    #pragma unroll
    for (int ck = 0; ck < 2; ck++) {
      gload_lds16(srcA[ck] + kt * 32, &lA[(w * 64 + ck * 256) * 8]);
      gload_lds16(srcB[ck] + kt * 32, &lB[(w * 64 + ck * 256) * 8]);
    }
    __syncthreads();
    bf16x8 af[4], bfr[4];
    #pragma unroll
    for (int m = 0; m < 4; m++) af[m] = *(const bf16x8*)&lA[(ra + m * 16) * 32 + ko];
    #pragma unroll
    for (int n = 0; n < 4; n++) bfr[n] = *(const bf16x8*)&lB[(rb + n * 16) * 32 + ko];
    #pragma unroll
    for (int m = 0; m < 4; m++)
      #pragma unroll
      for (int n = 0; n < 4; n++)
        acc[m][n] = __builtin_amdgcn_mfma_f32_16x16x32_bf16(af[m], bfr[n], acc[m][n], 0, 0, 0);
  }

  int rowbase = j0 + wr * 64;
  int colbase = bn * 128 + wc * 64;
  #pragma unroll
  for (int m = 0; m < 4; m++) {
    #pragma unroll
    for (int n = 0; n < 4; n++) {
      #pragma unroll
      for (int v = 0; v < 4; v++) {
        int r = rowbase + m * 16 + (l >> 4) * 4 + v;
        int cc = colbase + n * 16 + (l & 15);
        if (r < jend) {
          if (MODE == 1) {
            outF[(size_t)kc * (NTOK * R_DIM) + (size_t)r * R_DIM + cc] = acc[m][n][v];
          } else {
            size_t o = (size_t)perm[r] * O_DIM + cc;
            outF[o] += 2.0f * acc[m][n][v];
          }
        }
      }
    }
  }
}

// ---------------- reduce split-K partials -> bf16 H16s ----------------
__global__ void reduce_h(const float* __restrict__ hp, unsigned short* __restrict__ h16) {
  size_t g = (size_t)blockIdx.x * 256 + threadIdx.x;   // one float4 position
  const float4* h4 = (const float4*)hp;
  float4 s = h4[g];
  #pragma unroll
  for (int c = 1; c < KSPLIT; c++) {
    float4 p = h4[g + (size_t)c * (NTOK * R_DIM / 4)];
    s.x += p.x; s.y += p.y; s.z += p.z; s.w += p.w;
  }
  union { unsigned short h[4]; uint2 v; } u;
  u.h[0] = f2bf(s.x); u.h[1] = f2bf(s.y); u.h[2] = f2bf(s.z); u.h[3] = f2bf(s.w);
  ((uint2*)h16)[g] = u.v;
}

// ---------------- workspace layout (bytes) ----------------
#define X16_OFF   ((size_t)0)             // 8192*4096*2   = 67108864
#define W16_OFF   ((size_t)67108864)      // 4096*4096*2   = 33554432 (reused as HP)
#define A16T_OFF  ((size_t)100663296)     // 8*256*4096*2  = 16777216  [E][R][D]
#define B16T_OFF  ((size_t)117440512)     // 8*4096*256*2  = 16777216  [E][O][R]
#define H16S_OFF  ((size_t)134217728)     // 8192*256*2    = 4194304
#define PERM_OFF  ((size_t)138412032)     // 8192*4
#define TILEE_OFF ((size_t)138444800)     // 96*4
#define TILEJ0_OFF ((size_t)138445184)
#define TILEJE_OFF ((size_t)138445568)
#define NT_OFF    ((size_t)138445952)

extern "C" void kernel_launch(void* const* d_in, const int* in_sizes, int n_in,
                              void* d_out, int out_size, void* d_ws, size_t ws_size,
                              hipStream_t stream) {
  const float* x  = (const float*)d_in[0];   // [2,4096,4096]
  const float* wb = (const float*)d_in[1];   // [4096,4096]
  const float* la = (const float*)d_in[2];   // [8,4096,256]
  const float* lb = (const float*)d_in[3];   // [8,256,4096]
  const int* tok  = (const int*)d_in[4];     // [4096]
  float* out = (float*)d_out;                // [2,4096,4096]

  char* ws = (char*)d_ws;
  unsigned short* X16  = (unsigned short*)(ws + X16_OFF);
  unsigned short* W16  = (unsigned short*)(ws + W16_OFF);
  unsigned short* A16t = (unsigned short*)(ws + A16T_OFF);
  unsigned short* B16t = (unsigned short*)(ws + B16T_OFF);
  unsigned short* H16s = (unsigned short*)(ws + H16S_OFF);
  float* HP = (float*)(ws + W16_OFF);        // reuse W16 space after dense GEMM
  int* perm  = (int*)(ws + PERM_OFF);
  int* tl_e  = (int*)(ws + TILEE_OFF);
  int* tl_j0 = (int*)(ws + TILEJ0_OFF);
  int* tl_je = (int*)(ws + TILEJE_OFF);
  int* nt    = (int*)(ws + NT_OFF);

  // casts
  cast8<<<16384, 256, 0, stream>>>(x, X16);
  cast8<<<8192, 256, 0, stream>>>(wb, W16);
  transpose_cast<<<dim3(128, 8, 8), 256, 0, stream>>>(la, A16t, D_DIM, R_DIM);
  transpose_cast<<<dim3(8, 128, 8), 256, 0, stream>>>(lb, B16t, R_DIM, O_DIM);
  sort_tokens<<<1, 256, 0, stream>>>(tok, perm, tl_e, tl_j0, tl_je, nt);

  // base GEMM: out = X @ W^T   (256^2 pipelined kernel)
  gemm256_dense<<<512, 512, 0, stream>>>(X16, W16, out);

  // LoRA stage 1 (split-K x4): HP[kc] = partial(X[perm] @ A_e^T)  — overwrites W16 space
  gemm_nt<1><<<dim3(71, 2, KSPLIT), 256, 0, stream>>>(X16, A16t, HP,
                                                      perm, tl_e, tl_j0, tl_je, nt, D_DIM);
  reduce_h<<<2048, 256, 0, stream>>>(HP, H16s);

  // LoRA stage 2: out[perm] += 2 * H_sorted @ B_e^T
  gemm_nt<2><<<dim3(71, 32), 256, 0, stream>>>(H16s, B16t, out,
                                               perm, tl_e, tl_j0, tl_je, nt, R_DIM);
}

// Round 5
// 589.677 us; speedup vs baseline: 1.0828x; 1.0650x over previous
//
#include <hip/hip_runtime.h>

// Problem constants
#define S_TOK 4096
#define D_DIM 4096
#define O_DIM 4096
#define R_DIM 256
#define E_EXP 8
#define NTOK  8192   // B*S
#define KSPLIT 4

typedef __bf16 bf16x8 __attribute__((ext_vector_type(8)));
typedef float  f32x4  __attribute__((ext_vector_type(4)));

__device__ __forceinline__ unsigned short f2bf(float f) {
  unsigned int u = __float_as_uint(f);
  u += 0x7FFFu + ((u >> 16) & 1u);   // RNE (no NaN in data)
  return (unsigned short)(u >> 16);
}

__device__ __forceinline__ void gload_lds16(const unsigned short* g, unsigned short* l) {
  __builtin_amdgcn_global_load_lds((const __attribute__((address_space(1))) void*)g,
                                   (__attribute__((address_space(3))) void*)l, 16, 0, 0);
}

// Fused counted-wait + barrier as ONE volatile asm with memory clobber.
#define PIPE_FENCE(N)                                                        \
  do {                                                                       \
    asm volatile("s_waitcnt vmcnt(" #N ")\n\ts_barrier" ::: "memory");       \
    __builtin_amdgcn_sched_barrier(0);                                       \
  } while (0)

// ---------------- cast f32 -> bf16, 8 elems/thread ----------------
__global__ void cast8(const float* __restrict__ in, unsigned short* __restrict__ out) {
  size_t g = (size_t)blockIdx.x * 256 + threadIdx.x;
  const float4* i4 = (const float4*)in;
  float4 a = i4[g * 2], b = i4[g * 2 + 1];
  union { unsigned short h[8]; int4 v; } u;
  u.h[0] = f2bf(a.x); u.h[1] = f2bf(a.y); u.h[2] = f2bf(a.z); u.h[3] = f2bf(a.w);
  u.h[4] = f2bf(b.x); u.h[5] = f2bf(b.y); u.h[6] = f2bf(b.z); u.h[7] = f2bf(b.w);
  ((int4*)out)[g] = u.v;
}

// ------------- transpose+cast: in[e][P][Q] f32 -> out[e][Q][P] bf16 -------------
__global__ void transpose_cast(const float* __restrict__ in, unsigned short* __restrict__ out,
                               int P, int Q) {
  __shared__ unsigned short tile[32][33];
  int e = blockIdx.z;
  int pt = blockIdx.x * 32, qt = blockIdx.y * 32;
  const float* ie = in + (size_t)e * P * Q;
  unsigned short* oe = out + (size_t)e * P * Q;
  int tx = threadIdx.x & 31, ty = threadIdx.x >> 5;
  #pragma unroll
  for (int i = 0; i < 32; i += 8) {
    int p = pt + ty + i, q = qt + tx;
    tile[ty + i][tx] = f2bf(ie[(size_t)p * Q + q]);
  }
  __syncthreads();
  #pragma unroll
  for (int i = 0; i < 32; i += 8) {
    int q = qt + ty + i, p = pt + tx;
    oe[(size_t)q * P + p] = tile[tx][ty + i];
  }
}

// ------------- deterministic stable counting sort of tokens by expert -------------
__global__ void sort_tokens(const int* __restrict__ tt, int* __restrict__ token_perm,
                            int* __restrict__ tile_e, int* __restrict__ tile_j0,
                            int* __restrict__ tile_jend, int* __restrict__ ntiles_out) {
  __shared__ int ltt[S_TOK];
  __shared__ int lc[256 * 8];
  __shared__ int basee[8], cnte[8];
  __shared__ int ssl[S_TOK];
  int t = threadIdx.x;
  for (int s = t; s < S_TOK; s += 256) ltt[s] = tt[s];
  __syncthreads();
  int c[8] = {0,0,0,0,0,0,0,0};
  #pragma unroll
  for (int i = 0; i < 16; i++) { int e = ltt[t * 16 + i]; c[e]++; }
  #pragma unroll
  for (int e = 0; e < 8; e++) lc[t * 8 + e] = c[e];
  __syncthreads();
  if (t < 8) {
    int run = 0;
    for (int q = 0; q < 256; q++) { int tmp = lc[q * 8 + t]; lc[q * 8 + t] = run; run += tmp; }
    cnte[t] = run;
  }
  __syncthreads();
  if (t == 0) { int tot = 0; for (int e = 0; e < 8; e++) { basee[e] = tot; tot += cnte[e]; } }
  __syncthreads();
  int off[8];
  #pragma unroll
  for (int e = 0; e < 8; e++) off[e] = basee[e] + lc[t * 8 + e];
  #pragma unroll
  for (int i = 0; i < 16; i++) { int s = t * 16 + i; int e = ltt[s]; ssl[off[e]++] = s; }
  __syncthreads();
  for (int j = t; j < NTOK; j += 256) token_perm[j] = ((j & 1) << 12) + ssl[j >> 1];
  if (t == 0) {
    int nt = 0;
    for (int e = 0; e < 8; e++) {
      int js = 2 * basee[e], je = js + 2 * cnte[e];
      for (int j0 = js; j0 < je; j0 += 128) {
        tile_e[nt] = e; tile_j0[nt] = j0;
        tile_jend[nt] = (je < j0 + 128) ? je : (j0 + 128);
        nt++;
      }
    }
    *ntiles_out = nt;
  }
}

// ===================== 256x256 8-PHASE pipelined dense GEMM =====================
// C[8192][4096] = A @ B^T, bf16 in, f32 out. 8 waves (2Mx4N), wave tile 128x64.
// BK=64 split in two k-halves; LDS = 2 op x 2 ring x 2 khalf x 16KB = 128 KiB.
// Per K-tile: 4 phases, each {ds_read 4-8 || stage 1 half (2 gload_lds) ->
// s_barrier -> lgkmcnt(0) -> setprio(1) -> 16 MFMA -> setprio(0) -> vmcnt(8)+barrier}.
// Phase data: ph0/ph1 k-slice 0 (m-quad 0/1), ph2/ph3 k-slice 1.
// Stage map (5-6 phase lead): ph0 -> A-k1(t+1), ph1 -> B-k1(t+1),
//                             ph2 -> A-k0(t+2), ph3 -> B-k0(t+2).
// vmcnt ledger (2 loads/half/thread): vmcnt(8) allows 4 newest halves
// outstanding; need-by-phase always >= 5th newest (verified prologue/steady/tail).
// Tail fences: ...8,8,8,4 (tile 62) then 4,0,0 (tile 63).
__global__ __launch_bounds__(512, 2) void gemm256_dense(
    const unsigned short* __restrict__ A, const unsigned short* __restrict__ B,
    float* __restrict__ C) {
  __shared__ __align__(16) unsigned short ldsA[2][2][8192];  // [ring][khalf][256*32]
  __shared__ __align__(16) unsigned short ldsB[2][2][8192];
  int wg = blockIdx.x;
  wg = (wg & 7) * 64 + (wg >> 3);          // XCD swizzle (512 % 8 == 0, bijective)
  const int bm = wg & 31, bn = wg >> 5;    // 32 x 16 tiles
  const int tid = threadIdx.x, l = tid & 63, w = tid >> 6;
  const int wm = w >> 2, wn = w & 3;       // 2M x 4N wave grid

  // ---- staging source pointers (inverse-swizzled global, linear LDS dest) ----
  // half-tile = 256 rows x 32 elems (64B rows); chunk idx = ck*512+tid;
  // row = idx>>2, 16B chunk c = idx&3; swz(row) = ((row>>1)&3)<<4 bytes.
  const unsigned short* srcA0; const unsigned short* srcA1;
  const unsigned short* srcB0; const unsigned short* srcB1;
  {
    #pragma unroll
    for (int ck = 0; ck < 2; ck++) {
      int idx = ck * 512 + tid;
      int row = idx >> 2;
      int cb  = ((idx & 3) * 16) ^ (((row >> 1) & 3) << 4);   // swizzled byte col
      const unsigned short* a = A + (size_t)(bm * 256 + row) * 4096 + (cb >> 1);
      const unsigned short* b = B + (size_t)(bn * 256 + row) * 4096 + (cb >> 1);
      if (ck == 0) { srcA0 = a; srcB0 = b; } else { srcA1 = a; srcB1 = b; }
    }
  }
  const int d0 = tid * 8;  // LDS dest chunk (ushorts); ck=1 adds 4096

  // ---- swizzled ds_read byte-offsets within one 16KB slot ----
  const int lane15 = l & 15, kb16 = (l >> 4) * 16;
  int offA[8], offB[4];
  #pragma unroll
  for (int m = 0; m < 8; m++) {
    int r = wm * 128 + m * 16 + lane15;
    offA[m] = r * 64 + (kb16 ^ (((r >> 1) & 3) << 4));
  }
  #pragma unroll
  for (int n = 0; n < 4; n++) {
    int r = wn * 64 + n * 16 + lane15;
    offB[n] = r * 64 + (kb16 ^ (((r >> 1) & 3) << 4));
  }

  f32x4 acc[8][4];
  #pragma unroll
  for (int m = 0; m < 8; m++)
    #pragma unroll
    for (int n = 0; n < 4; n++) acc[m][n] = (f32x4){0.f, 0.f, 0.f, 0.f};

  bf16x8 af[4], bfr[4];

#define STAGE_A(tt, kh) do { int _o = (tt) * 64 + (kh) * 32;                  \
    gload_lds16(srcA0 + _o, &ldsA[(tt) & 1][kh][d0]);                         \
    gload_lds16(srcA1 + _o, &ldsA[(tt) & 1][kh][d0 + 4096]); } while (0)
#define STAGE_B(tt, kh) do { int _o = (tt) * 64 + (kh) * 32;                  \
    gload_lds16(srcB0 + _o, &ldsB[(tt) & 1][kh][d0]);                         \
    gload_lds16(srcB1 + _o, &ldsB[(tt) & 1][kh][d0 + 4096]); } while (0)
#define DS_READ_A(ring, q, ks) do {                                           \
    const char* _s = (const char*)&ldsA[ring][ks][0];                         \
    af[0] = *(const bf16x8*)(_s + offA[(q) * 4 + 0]);                         \
    af[1] = *(const bf16x8*)(_s + offA[(q) * 4 + 1]);                         \
    af[2] = *(const bf16x8*)(_s + offA[(q) * 4 + 2]);                         \
    af[3] = *(const bf16x8*)(_s + offA[(q) * 4 + 3]); } while (0)
#define DS_READ_B(ring, ks) do {                                              \
    const char* _s = (const char*)&ldsB[ring][ks][0];                         \
    bfr[0] = *(const bf16x8*)(_s + offB[0]);                                  \
    bfr[1] = *(const bf16x8*)(_s + offB[1]);                                  \
    bfr[2] = *(const bf16x8*)(_s + offB[2]);                                  \
    bfr[3] = *(const bf16x8*)(_s + offB[3]); } while (0)
#define MFMA16(q) do {                                                        \
    asm volatile("s_barrier" ::: "memory");                                   \
    asm volatile("s_waitcnt lgkmcnt(0)" ::: "memory");                        \
    __builtin_amdgcn_sched_barrier(0);                                        \
    __builtin_amdgcn_s_setprio(1);                                            \
    _Pragma("unroll")                                                         \
    for (int mm = 0; mm < 4; mm++)                                            \
      _Pragma("unroll")                                                       \
      for (int n = 0; n < 4; n++)                                             \
        acc[(q) * 4 + mm][n] = __builtin_amdgcn_mfma_f32_16x16x32_bf16(       \
            af[mm], bfr[n], acc[(q) * 4 + mm][n], 0, 0, 0);                   \
    __builtin_amdgcn_s_setprio(0); } while (0)

  // ---- prologue: 6 halves (12 loads); vmcnt(8) forces Ak0(0),Bk0(0) landed ----
  STAGE_A(0, 0); STAGE_B(0, 0); STAGE_A(0, 1); STAGE_B(0, 1);
  STAGE_A(1, 0); STAGE_B(1, 0);
  PIPE_FENCE(8);

  // ---- uniform loop: tiles 0..61 as ring pairs ----
  #pragma unroll 1
  for (int tp = 0; tp < 31; ++tp) {
    const int t0 = tp * 2, t1 = t0 + 1;
    // tile t0 (ring 0)
    DS_READ_B(0, 0); DS_READ_A(0, 0, 0); STAGE_A(t0 + 1, 1); MFMA16(0); PIPE_FENCE(8);
    DS_READ_A(0, 1, 0);                  STAGE_B(t0 + 1, 1); MFMA16(1); PIPE_FENCE(8);
    DS_READ_B(0, 1); DS_READ_A(0, 0, 1); STAGE_A(t0 + 2, 0); MFMA16(0); PIPE_FENCE(8);
    DS_READ_A(0, 1, 1);                  STAGE_B(t0 + 2, 0); MFMA16(1); PIPE_FENCE(8);
    // tile t1 (ring 1)
    DS_READ_B(1, 0); DS_READ_A(1, 0, 0); STAGE_A(t1 + 1, 1); MFMA16(0); PIPE_FENCE(8);
    DS_READ_A(1, 1, 0);                  STAGE_B(t1 + 1, 1); MFMA16(1); PIPE_FENCE(8);
    DS_READ_B(1, 1); DS_READ_A(1, 0, 1); STAGE_A(t1 + 2, 0); MFMA16(0); PIPE_FENCE(8);
    DS_READ_A(1, 1, 1);                  STAGE_B(t1 + 2, 0); MFMA16(1); PIPE_FENCE(8);
  }
  // ---- tile 62 (ring 0): stages only k1(63); fence drops to 4 at end ----
  DS_READ_B(0, 0); DS_READ_A(0, 0, 0); STAGE_A(63, 1); MFMA16(0); PIPE_FENCE(8);
  DS_READ_A(0, 1, 0);                  STAGE_B(63, 1); MFMA16(1); PIPE_FENCE(8);
  DS_READ_B(0, 1); DS_READ_A(0, 0, 1);                 MFMA16(0); PIPE_FENCE(8);
  DS_READ_A(0, 1, 1);                                  MFMA16(1); PIPE_FENCE(4);
  // ---- tile 63 (ring 1): descending drain 4 -> 0 ----
  DS_READ_B(1, 0); DS_READ_A(1, 0, 0); MFMA16(0); PIPE_FENCE(4);
  DS_READ_A(1, 1, 0);                  MFMA16(1); PIPE_FENCE(0);
  DS_READ_B(1, 1); DS_READ_A(1, 0, 1); MFMA16(0); PIPE_FENCE(0);
  DS_READ_A(1, 1, 1);                  MFMA16(1);

#undef STAGE_A
#undef STAGE_B
#undef DS_READ_A
#undef DS_READ_B
#undef MFMA16

  const int rowbase = bm * 256 + wm * 128;
  const int colbase = bn * 256 + wn * 64;
  #pragma unroll
  for (int m = 0; m < 8; m++)
    #pragma unroll
    for (int n = 0; n < 4; n++)
      #pragma unroll
      for (int v = 0; v < 4; v++) {
        int r = rowbase + m * 16 + (l >> 4) * 4 + v;
        int cc = colbase + n * 16 + lane15;
        C[(size_t)r * O_DIM + cc] = acc[m][n][v];
      }
}

// ------------- 128x128 skeleton for the LoRA GEMMs -------------
// MODE 1: Hp[kc][j][r] = partial( X[perm[j]] @ A16t[e]^T ) over K-chunk kc (f32 out)
// MODE 2: out_f32[perm[j]] += 2 * H16s @ B16t[e]^T   (scatter-RMW, predicated)
template<int MODE>
__global__ __launch_bounds__(256, 2) void gemm_nt(
    const unsigned short* __restrict__ Aop, const unsigned short* __restrict__ Bop,
    float* __restrict__ outF,
    const int* __restrict__ perm, const int* __restrict__ tile_e,
    const int* __restrict__ tile_j0, const int* __restrict__ tile_jend,
    const int* __restrict__ ntiles, int K) {
  int bm = blockIdx.x, bn = blockIdx.y;
  if (bm >= *ntiles) return;
  int e = tile_e[bm], j0 = tile_j0[bm], jend = tile_jend[bm];
  const int kc = (MODE == 1) ? blockIdx.z : 0;
  const int t = threadIdx.x;
  const int l = t & 63, w = t >> 6;
  __shared__ __align__(16) unsigned short lA[128 * 32];
  __shared__ __align__(16) unsigned short lB[128 * 32];

  const unsigned short* srcA[2];
  const unsigned short* srcB[2];
  #pragma unroll
  for (int ck = 0; ck < 2; ck++) {
    int idx = t + ck * 256;
    int lrow = idx >> 2, lk = (idx & 3) * 8;
    int j = j0 + lrow; if (j > jend - 1) j = jend - 1;
    int grow = (MODE == 1) ? perm[j] : j;
    srcA[ck] = Aop + (size_t)grow * K + lk + kc * 1024;
    int bcol = bn * 128 + lrow;
    const unsigned short* bp = Bop;
    if (MODE == 1) bp += (size_t)e * R_DIM * D_DIM;
    if (MODE == 2) bp += (size_t)e * O_DIM * R_DIM;
    srcB[ck] = bp + (size_t)bcol * K + lk + kc * 1024;
  }

  f32x4 acc[4][4];
  #pragma unroll
  for (int m = 0; m < 4; m++)
    #pragma unroll
    for (int n = 0; n < 4; n++) acc[m][n] = (f32x4){0.f, 0.f, 0.f, 0.f};

  const int wr = w >> 1, wc = w & 1;
  const int ra = wr * 64 + (l & 15);
  const int rb = wc * 64 + (l & 15);
  const int ko = (l >> 4) * 8;

  const int nk = (MODE == 1) ? (1024 / 32) : (K / 32);
  for (int kt = 0; kt < nk; kt++) {
    __syncthreads();
    #pragma unroll
    for (int ck = 0; ck < 2; ck++) {
      gload_lds16(srcA[ck] + kt * 32, &lA[(w * 64 + ck * 256) * 8]);
      gload_lds16(srcB[ck] + kt * 32, &lB[(w * 64 + ck * 256) * 8]);
    }
    __syncthreads();
    bf16x8 af[4], bfr[4];
    #pragma unroll
    for (int m = 0; m < 4; m++) af[m] = *(const bf16x8*)&lA[(ra + m * 16) * 32 + ko];
    #pragma unroll
    for (int n = 0; n < 4; n++) bfr[n] = *(const bf16x8*)&lB[(rb + n * 16) * 32 + ko];
    #pragma unroll
    for (int m = 0; m < 4; m++)
      #pragma unroll
      for (int n = 0; n < 4; n++)
        acc[m][n] = __builtin_amdgcn_mfma_f32_16x16x32_bf16(af[m], bfr[n], acc[m][n], 0, 0, 0);
  }

  int rowbase = j0 + wr * 64;
  int colbase = bn * 128 + wc * 64;
  #pragma unroll
  for (int m = 0; m < 4; m++) {
    #pragma unroll
    for (int n = 0; n < 4; n++) {
      #pragma unroll
      for (int v = 0; v < 4; v++) {
        int r = rowbase + m * 16 + (l >> 4) * 4 + v;
        int cc = colbase + n * 16 + (l & 15);
        if (r < jend) {
          if (MODE == 1) {
            outF[(size_t)kc * (NTOK * R_DIM) + (size_t)r * R_DIM + cc] = acc[m][n][v];
          } else {
            size_t o = (size_t)perm[r] * O_DIM + cc;
            outF[o] += 2.0f * acc[m][n][v];
          }
        }
      }
    }
  }
}

// ---------------- reduce split-K partials -> bf16 H16s ----------------
__global__ void reduce_h(const float* __restrict__ hp, unsigned short* __restrict__ h16) {
  size_t g = (size_t)blockIdx.x * 256 + threadIdx.x;   // one float4 position
  const float4* h4 = (const float4*)hp;
  float4 s = h4[g];
  #pragma unroll
  for (int c = 1; c < KSPLIT; c++) {
    float4 p = h4[g + (size_t)c * (NTOK * R_DIM / 4)];
    s.x += p.x; s.y += p.y; s.z += p.z; s.w += p.w;
  }
  union { unsigned short h[4]; uint2 v; } u;
  u.h[0] = f2bf(s.x); u.h[1] = f2bf(s.y); u.h[2] = f2bf(s.z); u.h[3] = f2bf(s.w);
  ((uint2*)h16)[g] = u.v;
}

// ---------------- workspace layout (bytes) ----------------
#define X16_OFF   ((size_t)0)             // 8192*4096*2   = 67108864
#define W16_OFF   ((size_t)67108864)      // 4096*4096*2   = 33554432 (reused as HP)
#define A16T_OFF  ((size_t)100663296)     // 8*256*4096*2  = 16777216  [E][R][D]
#define B16T_OFF  ((size_t)117440512)     // 8*4096*256*2  = 16777216  [E][O][R]
#define H16S_OFF  ((size_t)134217728)     // 8192*256*2    = 4194304
#define PERM_OFF  ((size_t)138412032)     // 8192*4
#define TILEE_OFF ((size_t)138444800)     // 96*4
#define TILEJ0_OFF ((size_t)138445184)
#define TILEJE_OFF ((size_t)138445568)
#define NT_OFF    ((size_t)138445952)

extern "C" void kernel_launch(void* const* d_in, const int* in_sizes, int n_in,
                              void* d_out, int out_size, void* d_ws, size_t ws_size,
                              hipStream_t stream) {
  const float* x  = (const float*)d_in[0];   // [2,4096,4096]
  const float* wb = (const float*)d_in[1];   // [4096,4096]
  const float* la = (const float*)d_in[2];   // [8,4096,256]
  const float* lb = (const float*)d_in[3];   // [8,256,4096]
  const int* tok  = (const int*)d_in[4];     // [4096]
  float* out = (float*)d_out;                // [2,4096,4096]

  char* ws = (char*)d_ws;
  unsigned short* X16  = (unsigned short*)(ws + X16_OFF);
  unsigned short* W16  = (unsigned short*)(ws + W16_OFF);
  unsigned short* A16t = (unsigned short*)(ws + A16T_OFF);
  unsigned short* B16t = (unsigned short*)(ws + B16T_OFF);
  unsigned short* H16s = (unsigned short*)(ws + H16S_OFF);
  float* HP = (float*)(ws + W16_OFF);        // reuse W16 space after dense GEMM
  int* perm  = (int*)(ws + PERM_OFF);
  int* tl_e  = (int*)(ws + TILEE_OFF);
  int* tl_j0 = (int*)(ws + TILEJ0_OFF);
  int* tl_je = (int*)(ws + TILEJE_OFF);
  int* nt    = (int*)(ws + NT_OFF);

  // casts
  cast8<<<16384, 256, 0, stream>>>(x, X16);
  cast8<<<8192, 256, 0, stream>>>(wb, W16);
  transpose_cast<<<dim3(128, 8, 8), 256, 0, stream>>>(la, A16t, D_DIM, R_DIM);
  transpose_cast<<<dim3(8, 128, 8), 256, 0, stream>>>(lb, B16t, R_DIM, O_DIM);
  sort_tokens<<<1, 256, 0, stream>>>(tok, perm, tl_e, tl_j0, tl_je, nt);

  // base GEMM: out = X @ W^T   (256^2 8-phase pipelined kernel)
  gemm256_dense<<<512, 512, 0, stream>>>(X16, W16, out);

  // LoRA stage 1 (split-K x4): HP[kc] = partial(X[perm] @ A_e^T)  — overwrites W16 space
  gemm_nt<1><<<dim3(71, 2, KSPLIT), 256, 0, stream>>>(X16, A16t, HP,
                                                      perm, tl_e, tl_j0, tl_je, nt, D_DIM);
  reduce_h<<<2048, 256, 0, stream>>>(HP, H16s);

  // LoRA stage 2: out[perm] += 2 * H_sorted @ B_e^T
  gemm_nt<2><<<dim3(71, 32), 256, 0, stream>>>(H16s, B16t, out,
                                               perm, tl_e, tl_j0, tl_je, nt, R_DIM);
}